// Round 2
// baseline (384.327 us; speedup 1.0000x reference)
//
#include <hip/hip_runtime.h>
#include <hip/hip_bf16.h>
#include <math.h>

#define NV 131072
#define KOFF 27

typedef __attribute__((ext_vector_type(8))) short short8;
typedef __attribute__((ext_vector_type(4))) float floatx4;

__device__ inline float silu_f(float x) { return x / (1.0f + expf(-x)); }

// ---------- prep: W [k][cin][cout] f32 -> Wt [k][cout][cin] bf16; zero pad rows ----------
__global__ void prep_kernel(const float* __restrict__ W1, const float* __restrict__ W2,
                            __hip_bfloat16* __restrict__ W1t, __hip_bfloat16* __restrict__ W2t,
                            __hip_bfloat16* __restrict__ h0, __hip_bfloat16* __restrict__ h2) {
    int t = blockIdx.x * 256 + threadIdx.x;
    if (t < KOFF * 64 * 64) {
        int k = t >> 12, co = (t >> 6) & 63, ci = t & 63;
        int src = k * 4096 + ci * 64 + co;
        W1t[t] = __float2bfloat16(W1[src]);
        W2t[t] = __float2bfloat16(W2[src]);
    }
    if (t < 64) {  // padded zero row N for both staging buffers
        h0[NV * 64 + t] = __float2bfloat16(0.0f);
        h2[NV * 64 + t] = __float2bfloat16(0.0f);
    }
}

// ---------- transpose rulebook: nbr [row][k] -> nbr_t [k][row] (coalesced R/W via LDS) ----------
__global__ void nbrt_kernel(const int* __restrict__ nbr, int* __restrict__ nbr_t) {
    __shared__ int s[256 * KOFF];
    int t = threadIdx.x;
    int r0 = blockIdx.x * 256;
    for (int i = t; i < 256 * KOFF; i += 256) s[i] = nbr[r0 * KOFF + i];
    __syncthreads();
#pragma unroll
    for (int k = 0; k < KOFF; ++k) nbr_t[k * NV + r0 + t] = s[t * KOFF + k];
}

// ---------- FiLM: silu(emb) @ emb_W + emb_b -> ss [4,128]; one wave per output ----------
__global__ void film_kernel(const float* __restrict__ emb, const float* __restrict__ emb_W,
                            const float* __restrict__ emb_b, float* __restrict__ ss) {
    int wv = (blockIdx.x * 256 + threadIdx.x) >> 6;  // 0..511
    int lane = threadIdx.x & 63;
    int b = wv >> 7, c = wv & 127;
    float acc = 0.0f;
#pragma unroll
    for (int i = 0; i < 8; ++i) {
        int e = i * 64 + lane;
        acc += silu_f(emb[b * 512 + e]) * emb_W[e * 128 + c];
    }
#pragma unroll
    for (int m = 1; m < 64; m <<= 1) acc += __shfl_xor(acc, m);
    if (lane == 0) ss[wv] = acc + emb_b[c];
}

// ---------- LN1 + silu -> h0 bf16 (one wave per row) ----------
__global__ void ln1_kernel(const float* __restrict__ feats, const float* __restrict__ gamma,
                           const float* __restrict__ beta, __hip_bfloat16* __restrict__ h0) {
    int row = blockIdx.x * 4 + (threadIdx.x >> 6);
    int c = threadIdx.x & 63;
    float x = feats[row * 64 + c];
    float s = x;
#pragma unroll
    for (int m = 1; m < 64; m <<= 1) s += __shfl_xor(s, m);
    float mu = s * (1.0f / 64.0f);
    float d = x - mu;
    float q = d * d;
#pragma unroll
    for (int m = 1; m < 64; m <<= 1) q += __shfl_xor(q, m);
    float inv = rsqrtf(q * (1.0f / 64.0f) + 1e-6f);
    float hn = d * inv * gamma[c] + beta[c];
    h0[row * 64 + c] = __float2bfloat16(silu_f(hn));
}

// ---------- gather-MFMA sparse conv over 27 offsets ----------
// wave handles 32 rows x 64 cols; grid NV/128 blocks -> 4 waves/SIMD
// EPI=0: conv1 -> +b1, LN2, FiLM, silu -> dst_bf (bf16)
// EPI=1: conv2 -> +b2 + feats -> dst_f32
template <int EPI>
__global__ __launch_bounds__(256, 4) void conv_kernel(
    const __hip_bfloat16* __restrict__ hsrc,  // [NV+1, 64] bf16 (row NV = zeros)
    const __hip_bfloat16* __restrict__ Wt,    // [27, 64, 64] bf16, (k, cout, cin)
    const int* __restrict__ nbr_t,            // [27, NV]
    const int* __restrict__ batch_idx,        // [NV]
    const float* __restrict__ ss,             // [4, 128] (scale | shift)
    const float* __restrict__ bias,           // [64]
    const float* __restrict__ feats,          // [NV, 64] (EPI=1)
    __hip_bfloat16* __restrict__ dst_bf,
    float* __restrict__ dst_f32) {
    __shared__ float s_ss[512];
    int tid = threadIdx.x;
    if (EPI == 0) {
        for (int i = tid; i < 512; i += 256) s_ss[i] = ss[i];
        __syncthreads();
    }

    int lane = tid & 63;
    int wave = tid >> 6;
    int l15 = lane & 15;
    int quad = lane >> 4;
    int rowb = blockIdx.x * 128 + wave * 32;  // this wave's first row

    const short8* hs8 = (const short8*)hsrc;  // 8 bf16 = 16B
    const short8* w8 = (const short8*)Wt;     // [k*512 + cout*8 + ko8]
    const int* np0 = nbr_t + rowb + l15;
    const int* np1 = np0 + 16;

    floatx4 acc[2][4];
#pragma unroll
    for (int m = 0; m < 2; ++m)
#pragma unroll
        for (int n = 0; n < 4; ++n) acc[m][n] = (floatx4){0.f, 0.f, 0.f, 0.f};

    // pipeline preload: idx(k=0) -> A(k=0); idx(k=1) in flight
    int jc0 = np0[0], jc1 = np1[0];
    int jn0 = np0[NV], jn1 = np1[NV];
    short8 aq[2][2];
#pragma unroll
    for (int ks = 0; ks < 2; ++ks) {
        aq[ks][0] = hs8[jc0 * 8 + ks * 4 + quad];
        aq[ks][1] = hs8[jc1 * 8 + ks * 4 + quad];
    }

#pragma unroll 1
    for (int k = 0; k < KOFF; ++k) {
        const short8* wk = w8 + k * 512;
        // B fragments for this k (L1/L2-resident, shared across waves)
        short8 b0[4], b1[4];
#pragma unroll
        for (int n = 0; n < 4; ++n) b0[n] = wk[(n * 16 + l15) * 8 + quad];
#pragma unroll
        for (int n = 0; n < 4; ++n) b1[n] = wk[(n * 16 + l15) * 8 + 4 + quad];
        // prefetch idx(k+2) and A(k+1)
        int kpp = (k + 2 < KOFF) ? k + 2 : KOFF - 1;
        int j20 = np0[kpp * NV], j21 = np1[kpp * NV];
        short8 an[2][2];
#pragma unroll
        for (int ks = 0; ks < 2; ++ks) {
            an[ks][0] = hs8[jn0 * 8 + ks * 4 + quad];
            an[ks][1] = hs8[jn1 * 8 + ks * 4 + quad];
        }
        // MFMAs on current tiles
#pragma unroll
        for (int m = 0; m < 2; ++m)
#pragma unroll
            for (int n = 0; n < 4; ++n)
                acc[m][n] = __builtin_amdgcn_mfma_f32_16x16x32_bf16(aq[0][m], b0[n], acc[m][n], 0, 0, 0);
#pragma unroll
        for (int m = 0; m < 2; ++m)
#pragma unroll
            for (int n = 0; n < 4; ++n)
                acc[m][n] = __builtin_amdgcn_mfma_f32_16x16x32_bf16(aq[1][m], b1[n], acc[m][n], 0, 0, 0);
        // rotate pipeline
#pragma unroll
        for (int ks = 0; ks < 2; ++ks) {
            aq[ks][0] = an[ks][0];
            aq[ks][1] = an[ks][1];
        }
        jn0 = j20;
        jn1 = j21;
    }

    // epilogue: C/D layout col = lane&15, row = quad*4 + r
    float bias_v[4];
#pragma unroll
    for (int n = 0; n < 4; ++n) bias_v[n] = bias[n * 16 + l15];

#pragma unroll
    for (int m = 0; m < 2; ++m) {
#pragma unroll
        for (int r = 0; r < 4; ++r) {
            int row = rowb + m * 16 + quad * 4 + r;
            float v[4];
#pragma unroll
            for (int n = 0; n < 4; ++n) v[n] = acc[m][n][r] + bias_v[n];
            if (EPI == 0) {
                // LN (no affine) + FiLM + silu; stats across the 16 lanes sharing this quad
                float s = v[0] + v[1] + v[2] + v[3];
                float q = v[0] * v[0] + v[1] * v[1] + v[2] * v[2] + v[3] * v[3];
#pragma unroll
                for (int msk = 1; msk < 16; msk <<= 1) {
                    s += __shfl_xor(s, msk);
                    q += __shfl_xor(q, msk);
                }
                float mu = s * (1.0f / 64.0f);
                float var = q * (1.0f / 64.0f) - mu * mu;
                float inv = rsqrtf(var + 1e-6f);
                int b = batch_idx[row];
                const float* sb = s_ss + b * 128;
#pragma unroll
                for (int n = 0; n < 4; ++n) {
                    float hn = (v[n] - mu) * inv;
                    float x = hn * (1.0f + sb[n * 16 + l15]) + sb[64 + n * 16 + l15];
                    dst_bf[row * 64 + n * 16 + l15] = __float2bfloat16(silu_f(x));
                }
            } else {
#pragma unroll
                for (int n = 0; n < 4; ++n)
                    dst_f32[row * 64 + n * 16 + l15] = v[n] + feats[row * 64 + n * 16 + l15];
            }
        }
    }
}

extern "C" void kernel_launch(void* const* d_in, const int* in_sizes, int n_in,
                              void* d_out, int out_size, void* d_ws, size_t ws_size,
                              hipStream_t stream) {
    (void)in_sizes; (void)n_in; (void)out_size; (void)ws_size;
    const float* feats = (const float*)d_in[0];
    const float* emb   = (const float*)d_in[1];
    const float* gamma = (const float*)d_in[2];
    const float* beta  = (const float*)d_in[3];
    const float* W1    = (const float*)d_in[4];
    const float* b1    = (const float*)d_in[5];
    const float* W2    = (const float*)d_in[6];
    const float* b2    = (const float*)d_in[7];
    const float* emb_W = (const float*)d_in[8];
    const float* emb_b = (const float*)d_in[9];
    const int* nbr     = (const int*)d_in[10];
    const int* bidx    = (const int*)d_in[11];
    float* out = (float*)d_out;

    char* ws = (char*)d_ws;
    __hip_bfloat16* W1t = (__hip_bfloat16*)(ws);                          // 221184 B
    __hip_bfloat16* W2t = (__hip_bfloat16*)(ws + 221184);                 // 221184 B
    float* ss           = (float*)(ws + 442368);                          // 2048 B
    __hip_bfloat16* h0  = (__hip_bfloat16*)(ws + 444416);                 // [NV+1,64] = 16777344 B
    __hip_bfloat16* h2  = (__hip_bfloat16*)(ws + 444416 + 16777344);      // [NV+1,64]
    int* nbr_t          = (int*)(ws + 444416 + 2 * 16777344);             // [27,NV] = 14155776 B

    prep_kernel<<<(KOFF * 64 * 64 + 255) / 256, 256, 0, stream>>>(W1, W2, W1t, W2t, h0, h2);
    nbrt_kernel<<<NV / 256, 256, 0, stream>>>(nbr, nbr_t);
    film_kernel<<<128, 256, 0, stream>>>(emb, emb_W, emb_b, ss);
    ln1_kernel<<<NV / 4, 256, 0, stream>>>(feats, gamma, beta, h0);
    conv_kernel<0><<<NV / 128, 256, 0, stream>>>(h0, W1t, nbr_t, bidx, ss, b1, nullptr, h2, nullptr);
    conv_kernel<1><<<NV / 128, 256, 0, stream>>>(h2, W2t, nbr_t, bidx, ss, b2, feats, nullptr, out);
}

// Round 3
// 296.827 us; speedup vs baseline: 1.2948x; 1.2948x over previous
//
#include <hip/hip_runtime.h>
#include <hip/hip_bf16.h>
#include <math.h>

#define NV 131072
#define KOFF 27

typedef __attribute__((ext_vector_type(8))) short short8;
typedef __attribute__((ext_vector_type(4))) float floatx4;

__device__ inline float silu_f(float x) { return x / (1.0f + expf(-x)); }

// ---------- fused pre kernel: role-partitioned grid ----------
// [0,512): transpose nbr -> nbr_t ; [512,1024): LN1+silu -> h0
// [1024,1456): W1/W2 -> bf16 transposed ; [1456,1584): FiLM ; 1584: pad rows
__global__ void pre_kernel(const float* __restrict__ feats, const float* __restrict__ emb,
                           const float* __restrict__ gamma, const float* __restrict__ beta,
                           const float* __restrict__ W1, const float* __restrict__ W2,
                           const float* __restrict__ emb_W, const float* __restrict__ emb_b,
                           const int* __restrict__ nbr,
                           __hip_bfloat16* __restrict__ W1t, __hip_bfloat16* __restrict__ W2t,
                           float* __restrict__ ss, __hip_bfloat16* __restrict__ h0,
                           __hip_bfloat16* __restrict__ h2, int* __restrict__ nbr_t) {
    int gid = blockIdx.x, tid = threadIdx.x;
    if (gid < 512) {
        __shared__ int s[256 * KOFF];
        int r0 = gid * 256;
        for (int i = tid; i < 256 * KOFF; i += 256) s[i] = nbr[r0 * KOFF + i];
        __syncthreads();
#pragma unroll
        for (int k = 0; k < KOFF; ++k) nbr_t[k * NV + r0 + tid] = s[tid * KOFF + k];
    } else if (gid < 1024) {
        int base = (gid - 512) * 256;
        int wave = tid >> 6, c = tid & 63;
        for (int it = 0; it < 64; ++it) {
            int row = base + it * 4 + wave;
            float x = feats[row * 64 + c];
            float s = x;
#pragma unroll
            for (int m = 1; m < 64; m <<= 1) s += __shfl_xor(s, m);
            float mu = s * (1.0f / 64.0f);
            float d = x - mu, q = d * d;
#pragma unroll
            for (int m = 1; m < 64; m <<= 1) q += __shfl_xor(q, m);
            float inv = rsqrtf(q * (1.0f / 64.0f) + 1e-6f);
            h0[row * 64 + c] = __float2bfloat16(silu_f(d * inv * gamma[c] + beta[c]));
        }
    } else if (gid < 1456) {
        int t = (gid - 1024) * 256 + tid;  // < 110592
        int k = t >> 12, co = (t >> 6) & 63, ci = t & 63;
        int src = k * 4096 + ci * 64 + co;
        W1t[t] = __float2bfloat16(W1[src]);
        W2t[t] = __float2bfloat16(W2[src]);
    } else if (gid < 1584) {
        int wv = (gid - 1456) * 4 + (tid >> 6);  // 0..511
        int lane = tid & 63;
        int b = wv >> 7, c = wv & 127;
        float acc = 0.0f;
#pragma unroll
        for (int i = 0; i < 8; ++i) {
            int e = i * 64 + lane;
            acc += silu_f(emb[b * 512 + e]) * emb_W[e * 128 + c];
        }
#pragma unroll
        for (int m = 1; m < 64; m <<= 1) acc += __shfl_xor(acc, m);
        if (lane == 0) ss[wv] = acc + emb_b[c];
    } else {
        if (tid < 64) {
            h0[NV * 64 + tid] = __float2bfloat16(0.0f);
            h2[NV * 64 + tid] = __float2bfloat16(0.0f);
        }
    }
}

// ---------- gather-MFMA sparse conv; B staged in LDS (double-buffered, XOR-swizzled) ----------
// 64 rows/wave, 256 rows/block, 512 blocks -> 2 blocks/CU
template <int EPI>
__global__ __launch_bounds__(256, 2) void conv_kernel(
    const __hip_bfloat16* __restrict__ hsrc,  // [NV+1, 64] (row NV = zeros)
    const __hip_bfloat16* __restrict__ Wt,    // [27, 64, 64] (k, cout, cin) bf16
    const int* __restrict__ nbr_t,            // [27, NV]
    const int* __restrict__ batch_idx,        // [NV]
    const float* __restrict__ ss,             // [4, 128]
    const float* __restrict__ bias,           // [64]
    const float* __restrict__ feats,          // [NV, 64] (EPI=1)
    __hip_bfloat16* __restrict__ dst_bf, float* __restrict__ dst_f32) {
    __shared__ short sB[2][4096];  // 8KB per buffer
    __shared__ float s_ss[512];

    int tid = threadIdx.x, lane = tid & 63, wave = tid >> 6;
    int l15 = lane & 15, quad = lane >> 4;
    int rowb = blockIdx.x * 256, roww = rowb + wave * 64;

    if (EPI == 0)
        for (int i = tid; i < 512; i += 256) s_ss[i] = ss[i];

    const short8* hs8 = (const short8*)hsrc;
    const short8* w8 = (const short8*)Wt;  // global chunk index: k*512 + c
    short8* sb0 = (short8*)sB[0];
    short8* sb1 = (short8*)sB[1];

    // staging chunk positions (XOR swizzle: chunk c -> r*8 + (s^(r&7)), r=c>>3, s=c&7)
    int c0 = tid, c1 = tid + 256;
    int p0 = (c0 >> 3) * 8 + ((c0 & 7) ^ ((c0 >> 3) & 7));
    int p1 = (c1 >> 3) * 8 + ((c1 & 7) ^ ((c1 >> 3) & 7));

    // prologue: stage B(0) into buf0; preload B(1); idx(0), idx(1)
    short8 v0 = w8[c0], v1 = w8[c1];
    sb0[p0] = v0;
    sb0[p1] = v1;
    short8 Br0 = w8[512 + c0], Br1 = w8[512 + c1];
    int jc[4], jn[4];
#pragma unroll
    for (int m = 0; m < 4; ++m) jc[m] = nbr_t[roww + m * 16 + l15];
#pragma unroll
    for (int m = 0; m < 4; ++m) jn[m] = nbr_t[NV + roww + m * 16 + l15];

    floatx4 acc[4][4];
#pragma unroll
    for (int m = 0; m < 4; ++m)
#pragma unroll
        for (int n = 0; n < 4; ++n) acc[m][n] = (floatx4){0.f, 0.f, 0.f, 0.f};

    __asm__ __volatile__("s_waitcnt lgkmcnt(0)" ::: "memory");
    __builtin_amdgcn_s_barrier();

#pragma unroll 1
    for (int k = 0; k < KOFF; ++k) {
        // 1. A gathers first (so pre-MFMA wait leaves later prefetches in flight)
        short8 a[4][2];
#pragma unroll
        for (int m = 0; m < 4; ++m) {
#pragma unroll
            for (int ks = 0; ks < 2; ++ks) a[m][ks] = hs8[jc[m] * 8 + ks * 4 + quad];
        }
        // 2. prefetch B(k+2) and idx(k+2)
        int kp2 = (k + 2 <= 26) ? k + 2 : 26;
        short8 Bn0 = w8[kp2 * 512 + c0], Bn1 = w8[kp2 * 512 + c1];
        int j2[4];
#pragma unroll
        for (int m = 0; m < 4; ++m) j2[m] = nbr_t[kp2 * NV + roww + m * 16 + l15];
        // 3. B fragments from LDS (swizzled)
        const short8* cb = (k & 1) ? sb1 : sb0;
        short8 bf[2][4];
#pragma unroll
        for (int ks = 0; ks < 2; ++ks) {
#pragma unroll
            for (int n = 0; n < 4; ++n) {
                int row = n * 16 + l15;
                bf[ks][n] = cb[row * 8 + ((ks * 4 + quad) ^ (row & 7))];
            }
        }
        // 4. MFMAs
#pragma unroll
        for (int ks = 0; ks < 2; ++ks)
#pragma unroll
            for (int m = 0; m < 4; ++m)
#pragma unroll
                for (int n = 0; n < 4; ++n)
                    acc[m][n] = __builtin_amdgcn_mfma_f32_16x16x32_bf16(a[m][ks], bf[ks][n], acc[m][n], 0, 0, 0);
        // 5. stage B(k+1) into the other buffer; lgkm-only barrier (keep vmem in flight)
        short8* ob = (k & 1) ? sb0 : sb1;
        ob[p0] = Br0;
        ob[p1] = Br1;
        __asm__ __volatile__("s_waitcnt lgkmcnt(0)" ::: "memory");
        __builtin_amdgcn_s_barrier();
        Br0 = Bn0;
        Br1 = Bn1;
#pragma unroll
        for (int m = 0; m < 4; ++m) { jc[m] = jn[m]; jn[m] = j2[m]; }
    }

    // epilogue: C/D layout col = lane&15, row = quad*4 + r
    float bias_v[4];
#pragma unroll
    for (int n = 0; n < 4; ++n) bias_v[n] = bias[n * 16 + l15];

#pragma unroll
    for (int m = 0; m < 4; ++m) {
#pragma unroll
        for (int r = 0; r < 4; ++r) {
            int row = roww + m * 16 + quad * 4 + r;
            float v[4];
#pragma unroll
            for (int n = 0; n < 4; ++n) v[n] = acc[m][n][r] + bias_v[n];
            if (EPI == 0) {
                float s = v[0] + v[1] + v[2] + v[3];
                float q = v[0] * v[0] + v[1] * v[1] + v[2] * v[2] + v[3] * v[3];
#pragma unroll
                for (int msk = 1; msk < 16; msk <<= 1) {
                    s += __shfl_xor(s, msk);
                    q += __shfl_xor(q, msk);
                }
                float mu = s * (1.0f / 64.0f);
                float var = q * (1.0f / 64.0f) - mu * mu;
                float inv = rsqrtf(var + 1e-6f);
                int b = batch_idx[row];
                const float* sb = s_ss + b * 128;
#pragma unroll
                for (int n = 0; n < 4; ++n) {
                    float hn = (v[n] - mu) * inv;
                    float x = hn * (1.0f + sb[n * 16 + l15]) + sb[64 + n * 16 + l15];
                    dst_bf[row * 64 + n * 16 + l15] = __float2bfloat16(silu_f(x));
                }
            } else {
#pragma unroll
                for (int n = 0; n < 4; ++n)
                    dst_f32[row * 64 + n * 16 + l15] = v[n] + feats[row * 64 + n * 16 + l15];
            }
        }
    }
}

extern "C" void kernel_launch(void* const* d_in, const int* in_sizes, int n_in,
                              void* d_out, int out_size, void* d_ws, size_t ws_size,
                              hipStream_t stream) {
    (void)in_sizes; (void)n_in; (void)out_size; (void)ws_size;
    const float* feats = (const float*)d_in[0];
    const float* emb   = (const float*)d_in[1];
    const float* gamma = (const float*)d_in[2];
    const float* beta  = (const float*)d_in[3];
    const float* W1    = (const float*)d_in[4];
    const float* b1    = (const float*)d_in[5];
    const float* W2    = (const float*)d_in[6];
    const float* b2    = (const float*)d_in[7];
    const float* emb_W = (const float*)d_in[8];
    const float* emb_b = (const float*)d_in[9];
    const int* nbr     = (const int*)d_in[10];
    const int* bidx    = (const int*)d_in[11];
    float* out = (float*)d_out;

    char* ws = (char*)d_ws;
    __hip_bfloat16* W1t = (__hip_bfloat16*)(ws);                       // 221184 B
    __hip_bfloat16* W2t = (__hip_bfloat16*)(ws + 221184);              // 221184 B
    float* ss           = (float*)(ws + 442368);                       // 2048 B
    __hip_bfloat16* h0  = (__hip_bfloat16*)(ws + 444416);              // [NV+1,64]
    __hip_bfloat16* h2  = (__hip_bfloat16*)(ws + 444416 + 16777344);   // [NV+1,64]
    int* nbr_t          = (int*)(ws + 444416 + 2 * 16777344);          // [27,NV]

    pre_kernel<<<1585, 256, 0, stream>>>(feats, emb, gamma, beta, W1, W2, emb_W, emb_b,
                                         nbr, W1t, W2t, ss, h0, h2, nbr_t);
    conv_kernel<0><<<512, 256, 0, stream>>>(h0, W1t, nbr_t, bidx, ss, b1, nullptr, h2, nullptr);
    conv_kernel<1><<<512, 256, 0, stream>>>(h2, W2t, nbr_t, bidx, ss, b2, feats, nullptr, out);
}

// Round 4
// 197.758 us; speedup vs baseline: 1.9434x; 1.5010x over previous
//
#include <hip/hip_runtime.h>
#include <hip/hip_bf16.h>
#include <math.h>

#define NV 131072
#define KOFF 27
#define ZROWS 64  // zero-pad region rows (spread hot line)

typedef __attribute__((ext_vector_type(8))) short short8;
typedef __attribute__((ext_vector_type(4))) float floatx4;

__device__ inline float silu_f(float x) { return x / (1.0f + expf(-x)); }

// ---------- fused pre kernel: role-partitioned grid ----------
// [0,512): transpose nbr -> nbr_t (with zero-region remap)
// [512,2560): LN1+silu -> h0   (4 rows per block, one per wave)
// [2560,2992): W1/W2 -> bf16 transposed
// [2992,3120): FiLM
// [3120,3122): zero-pad regions of h0/h2
__global__ void pre_kernel(const float* __restrict__ feats, const float* __restrict__ emb,
                           const float* __restrict__ gamma, const float* __restrict__ beta,
                           const float* __restrict__ W1, const float* __restrict__ W2,
                           const float* __restrict__ emb_W, const float* __restrict__ emb_b,
                           const int* __restrict__ nbr,
                           __hip_bfloat16* __restrict__ W1t, __hip_bfloat16* __restrict__ W2t,
                           float* __restrict__ ss, __hip_bfloat16* __restrict__ h0,
                           __hip_bfloat16* __restrict__ h2, int* __restrict__ nbr_t) {
    int gid = blockIdx.x, tid = threadIdx.x;
    if (gid < 512) {
        __shared__ int s[256 * KOFF];
        int r0 = gid * 256;
        for (int i = tid; i < 256 * KOFF; i += 256) s[i] = nbr[r0 * KOFF + i];
        __syncthreads();
        int r = r0 + tid;
        int zr = NV + ((r >> 7) & (ZROWS - 1));  // per-conv-block zero row
#pragma unroll
        for (int k = 0; k < KOFF; ++k) {
            int v = s[tid * KOFF + k];
            nbr_t[k * NV + r] = (v == NV) ? zr : v;
        }
    } else if (gid < 2560) {
        int row = (gid - 512) * 4 + (tid >> 6);
        int c = tid & 63;
        float x = feats[row * 64 + c];
        float s = x;
#pragma unroll
        for (int m = 1; m < 64; m <<= 1) s += __shfl_xor(s, m);
        float mu = s * (1.0f / 64.0f);
        float d = x - mu, q = d * d;
#pragma unroll
        for (int m = 1; m < 64; m <<= 1) q += __shfl_xor(q, m);
        float inv = rsqrtf(q * (1.0f / 64.0f) + 1e-6f);
        h0[row * 64 + c] = __float2bfloat16(silu_f(d * inv * gamma[c] + beta[c]));
    } else if (gid < 2992) {
        int t = (gid - 2560) * 256 + tid;  // < 110592
        int k = t >> 12, co = (t >> 6) & 63, ci = t & 63;
        int src = k * 4096 + ci * 64 + co;
        W1t[t] = __float2bfloat16(W1[src]);
        W2t[t] = __float2bfloat16(W2[src]);
    } else if (gid < 3120) {
        int wv = (gid - 2992) * 4 + (tid >> 6);  // 0..511
        int lane = tid & 63;
        int b = wv >> 7, c = wv & 127;
        float acc = 0.0f;
#pragma unroll
        for (int i = 0; i < 8; ++i) {
            int e = i * 64 + lane;
            acc += silu_f(emb[b * 512 + e]) * emb_W[e * 128 + c];
        }
#pragma unroll
        for (int m = 1; m < 64; m <<= 1) acc += __shfl_xor(acc, m);
        if (lane == 0) ss[wv] = acc + emb_b[c];
    } else {
        int t = (gid - 3120) * 256 + tid;  // 0..511 chunks of 16B
        if (t < ZROWS * 8) {
            short8 z = (short8){0, 0, 0, 0, 0, 0, 0, 0};
            ((short8*)h0)[NV * 8 + t] = z;
            ((short8*)h2)[NV * 8 + t] = z;
        }
    }
}

// ---------- gather-MFMA sparse conv; B in LDS; A pipelined across the barrier ----------
// 32 rows/wave, 128 rows/block, 1024 blocks
template <int EPI>
__global__ __launch_bounds__(256) void conv_kernel(
    const __hip_bfloat16* __restrict__ hsrc,  // [NV+ZROWS, 64] (rows >= NV are zeros)
    const __hip_bfloat16* __restrict__ Wt,    // [27, 64, 64] (k, cout, cin) bf16
    const int* __restrict__ nbr_t,            // [27, NV] (invalid remapped to zero region)
    const int* __restrict__ batch_idx,        // [NV]
    const float* __restrict__ ss,             // [4, 128]
    const float* __restrict__ bias,           // [64]
    const float* __restrict__ feats,          // [NV, 64] (EPI=1)
    __hip_bfloat16* __restrict__ dst_bf, float* __restrict__ dst_f32) {
    __shared__ short sB[2][4096];  // 8KB per buffer
    __shared__ float s_ss[512];

    int tid = threadIdx.x, lane = tid & 63, wave = tid >> 6;
    int l15 = lane & 15, quad = lane >> 4;
    int roww = blockIdx.x * 128 + wave * 32;

    if (EPI == 0)
        for (int i = tid; i < 512; i += 256) s_ss[i] = ss[i];

    const short8* hs8 = (const short8*)hsrc;
    const short8* w8 = (const short8*)Wt;
    short8* sb0 = (short8*)sB[0];
    short8* sb1 = (short8*)sB[1];

    // staging chunk positions (XOR swizzle: chunk c -> r*8 + (s^(r&7)))
    int c0 = tid, c1 = tid + 256;
    int p0 = (c0 >> 3) * 8 + ((c0 & 7) ^ ((c0 >> 3) & 7));
    int p1 = (c1 >> 3) * 8 + ((c1 & 7) ^ ((c1 >> 3) & 7));

    // prologue: idx(0), idx(1); A(0) in flight; B(0) -> LDS; B(1) -> regs
    int jc[2], jn[2];
#pragma unroll
    for (int m = 0; m < 2; ++m) jc[m] = nbr_t[roww + m * 16 + l15];
#pragma unroll
    for (int m = 0; m < 2; ++m) jn[m] = nbr_t[NV + roww + m * 16 + l15];
    sb0[p0] = w8[c0];
    sb0[p1] = w8[c1];
    short8 Br0 = w8[512 + c0], Br1 = w8[512 + c1];
    short8 ac[2][2];
#pragma unroll
    for (int m = 0; m < 2; ++m)
#pragma unroll
        for (int ks = 0; ks < 2; ++ks) ac[m][ks] = hs8[jc[m] * 8 + ks * 4 + quad];

    floatx4 acc[2][4];
#pragma unroll
    for (int m = 0; m < 2; ++m)
#pragma unroll
        for (int n = 0; n < 4; ++n) acc[m][n] = (floatx4){0.f, 0.f, 0.f, 0.f};

    __asm__ __volatile__("s_waitcnt lgkmcnt(0)" ::: "memory");
    __builtin_amdgcn_s_barrier();

#pragma unroll 1
    for (int k = 0; k < KOFF; ++k) {
        // 1. issue A(k+1) gathers (consumed NEXT iter -> latency crosses the barrier)
        short8 an[2][2];
#pragma unroll
        for (int m = 0; m < 2; ++m)
#pragma unroll
            for (int ks = 0; ks < 2; ++ks) an[m][ks] = hs8[jn[m] * 8 + ks * 4 + quad];
        // 2. prefetch B(k+2), idx(k+2)
        int kp2 = (k + 2 < KOFF) ? k + 2 : KOFF - 1;
        short8 Bn0 = w8[kp2 * 512 + c0], Bn1 = w8[kp2 * 512 + c1];
        int j2[2];
#pragma unroll
        for (int m = 0; m < 2; ++m) j2[m] = nbr_t[kp2 * NV + roww + m * 16 + l15];
        // 3. B(k) fragments from LDS
        const short8* cb = (k & 1) ? sb1 : sb0;
        short8 bf[2][4];
#pragma unroll
        for (int ks = 0; ks < 2; ++ks)
#pragma unroll
            for (int n = 0; n < 4; ++n) {
                int row = n * 16 + l15;
                bf[ks][n] = cb[row * 8 + ((ks * 4 + quad) ^ (row & 7))];
            }
        // 4. stage B(k+1) into other buffer; lgkm-only barrier (vmem stays in flight)
        short8* ob = (k & 1) ? sb0 : sb1;
        ob[p0] = Br0;
        ob[p1] = Br1;
        __asm__ __volatile__("s_waitcnt lgkmcnt(0)" ::: "memory");
        __builtin_amdgcn_s_barrier();
        // 5. MFMAs on A(k) (already resident) x B(k)
#pragma unroll
        for (int ks = 0; ks < 2; ++ks)
#pragma unroll
            for (int m = 0; m < 2; ++m)
#pragma unroll
                for (int n = 0; n < 4; ++n)
                    acc[m][n] = __builtin_amdgcn_mfma_f32_16x16x32_bf16(ac[m][ks], bf[ks][n], acc[m][n], 0, 0, 0);
        // 6. rotate pipeline
        Br0 = Bn0;
        Br1 = Bn1;
#pragma unroll
        for (int m = 0; m < 2; ++m) {
            jc[m] = jn[m];
            jn[m] = j2[m];
#pragma unroll
            for (int ks = 0; ks < 2; ++ks) ac[m][ks] = an[m][ks];
        }
    }

    // epilogue: C/D layout col = lane&15, row = quad*4 + r
    float bias_v[4];
#pragma unroll
    for (int n = 0; n < 4; ++n) bias_v[n] = bias[n * 16 + l15];

#pragma unroll
    for (int m = 0; m < 2; ++m) {
#pragma unroll
        for (int r = 0; r < 4; ++r) {
            int row = roww + m * 16 + quad * 4 + r;
            float v[4];
#pragma unroll
            for (int n = 0; n < 4; ++n) v[n] = acc[m][n][r] + bias_v[n];
            if (EPI == 0) {
                float s = v[0] + v[1] + v[2] + v[3];
                float q = v[0] * v[0] + v[1] * v[1] + v[2] * v[2] + v[3] * v[3];
#pragma unroll
                for (int msk = 1; msk < 16; msk <<= 1) {
                    s += __shfl_xor(s, msk);
                    q += __shfl_xor(q, msk);
                }
                float mu = s * (1.0f / 64.0f);
                float var = q * (1.0f / 64.0f) - mu * mu;
                float inv = rsqrtf(var + 1e-6f);
                int b = batch_idx[row];
                const float* sb = s_ss + b * 128;
#pragma unroll
                for (int n = 0; n < 4; ++n) {
                    float hn = (v[n] - mu) * inv;
                    float x = hn * (1.0f + sb[n * 16 + l15]) + sb[64 + n * 16 + l15];
                    dst_bf[row * 64 + n * 16 + l15] = __float2bfloat16(silu_f(x));
                }
            } else {
#pragma unroll
                for (int n = 0; n < 4; ++n)
                    dst_f32[row * 64 + n * 16 + l15] = v[n] + feats[row * 64 + n * 16 + l15];
            }
        }
    }
}

extern "C" void kernel_launch(void* const* d_in, const int* in_sizes, int n_in,
                              void* d_out, int out_size, void* d_ws, size_t ws_size,
                              hipStream_t stream) {
    (void)in_sizes; (void)n_in; (void)out_size; (void)ws_size;
    const float* feats = (const float*)d_in[0];
    const float* emb   = (const float*)d_in[1];
    const float* gamma = (const float*)d_in[2];
    const float* beta  = (const float*)d_in[3];
    const float* W1    = (const float*)d_in[4];
    const float* b1    = (const float*)d_in[5];
    const float* W2    = (const float*)d_in[6];
    const float* b2    = (const float*)d_in[7];
    const float* emb_W = (const float*)d_in[8];
    const float* emb_b = (const float*)d_in[9];
    const int* nbr     = (const int*)d_in[10];
    const int* bidx    = (const int*)d_in[11];
    float* out = (float*)d_out;

    const size_t HSZ = (size_t)(NV + ZROWS) * 64 * 2;  // bf16 buffer with zero region
    char* ws = (char*)d_ws;
    __hip_bfloat16* W1t = (__hip_bfloat16*)(ws);                  // 221184 B
    __hip_bfloat16* W2t = (__hip_bfloat16*)(ws + 221184);         // 221184 B
    float* ss           = (float*)(ws + 442368);                  // 2048 B
    __hip_bfloat16* h0  = (__hip_bfloat16*)(ws + 444416);
    __hip_bfloat16* h2  = (__hip_bfloat16*)(ws + 444416 + HSZ);
    int* nbr_t          = (int*)(ws + 444416 + 2 * HSZ);          // [27,NV]

    pre_kernel<<<3122, 256, 0, stream>>>(feats, emb, gamma, beta, W1, W2, emb_W, emb_b,
                                         nbr, W1t, W2t, ss, h0, h2, nbr_t);
    conv_kernel<0><<<1024, 256, 0, stream>>>(h0, W1t, nbr_t, bidx, ss, b1, nullptr, h2, nullptr);
    conv_kernel<1><<<1024, 256, 0, stream>>>(h2, W2t, nbr_t, bidx, ss, b2, feats, nullptr, out);
}

// Round 5
// 186.238 us; speedup vs baseline: 2.0636x; 1.0619x over previous
//
#include <hip/hip_runtime.h>
#include <hip/hip_bf16.h>
#include <math.h>

#define NV 131072
#define KOFF 27
#define ZROWS 64  // zero-pad region rows (spread hot line)

typedef __attribute__((ext_vector_type(8))) short short8;
typedef __attribute__((ext_vector_type(4))) float floatx4;

__device__ inline float silu_f(float x) { return x / (1.0f + expf(-x)); }

// ---------- fused pre kernel: role-partitioned grid ----------
// [0,512): transpose nbr -> nbr_t as BYTE offsets (row*128), zero-region remap
// [512,2560): LN1+silu -> h0
// [2560,2992): W1/W2 -> bf16 transposed
// [2992,3120): FiLM
// [3120,3122): zero-pad regions of h0/h2
__global__ void pre_kernel(const float* __restrict__ feats, const float* __restrict__ emb,
                           const float* __restrict__ gamma, const float* __restrict__ beta,
                           const float* __restrict__ W1, const float* __restrict__ W2,
                           const float* __restrict__ emb_W, const float* __restrict__ emb_b,
                           const int* __restrict__ nbr,
                           __hip_bfloat16* __restrict__ W1t, __hip_bfloat16* __restrict__ W2t,
                           float* __restrict__ ss, __hip_bfloat16* __restrict__ h0,
                           __hip_bfloat16* __restrict__ h2, unsigned int* __restrict__ nbr_t) {
    int gid = blockIdx.x, tid = threadIdx.x;
    if (gid < 512) {
        __shared__ int s[256 * KOFF];
        int r0 = gid * 256;
        for (int i = tid; i < 256 * KOFF; i += 256) s[i] = nbr[r0 * KOFF + i];
        __syncthreads();
        int r = r0 + tid;
        int zr = NV + ((r >> 7) & (ZROWS - 1));  // per-conv-block zero row
#pragma unroll
        for (int k = 0; k < KOFF; ++k) {
            int v = s[tid * KOFF + k];
            nbr_t[k * NV + r] = (unsigned int)(((v == NV) ? zr : v) << 7);  // byte offset
        }
    } else if (gid < 2560) {
        int row = (gid - 512) * 4 + (tid >> 6);
        int c = tid & 63;
        float x = feats[row * 64 + c];
        float s = x;
#pragma unroll
        for (int m = 1; m < 64; m <<= 1) s += __shfl_xor(s, m);
        float mu = s * (1.0f / 64.0f);
        float d = x - mu, q = d * d;
#pragma unroll
        for (int m = 1; m < 64; m <<= 1) q += __shfl_xor(q, m);
        float inv = rsqrtf(q * (1.0f / 64.0f) + 1e-6f);
        h0[row * 64 + c] = __float2bfloat16(silu_f(d * inv * gamma[c] + beta[c]));
    } else if (gid < 2992) {
        int t = (gid - 2560) * 256 + tid;  // < 110592
        int k = t >> 12, co = (t >> 6) & 63, ci = t & 63;
        int src = k * 4096 + ci * 64 + co;
        W1t[t] = __float2bfloat16(W1[src]);
        W2t[t] = __float2bfloat16(W2[src]);
    } else if (gid < 3120) {
        int wv = (gid - 2992) * 4 + (tid >> 6);  // 0..511
        int lane = tid & 63;
        int b = wv >> 7, c = wv & 127;
        float acc = 0.0f;
#pragma unroll
        for (int i = 0; i < 8; ++i) {
            int e = i * 64 + lane;
            acc += silu_f(emb[b * 512 + e]) * emb_W[e * 128 + c];
        }
#pragma unroll
        for (int m = 1; m < 64; m <<= 1) acc += __shfl_xor(acc, m);
        if (lane == 0) ss[wv] = acc + emb_b[c];
    } else {
        int t = (gid - 3120) * 256 + tid;
        if (t < ZROWS * 8) {
            short8 z = (short8){0, 0, 0, 0, 0, 0, 0, 0};
            ((short8*)h0)[NV * 8 + t] = z;
            ((short8*)h2)[NV * 8 + t] = z;
        }
    }
}

// ---------- gather-MFMA sparse conv; unrolled x2, byte-offset rulebook ----------
// 32 rows/wave, 128 rows/block, 1024 blocks
template <int EPI>
__global__ __launch_bounds__(256, 4) void conv_kernel(
    const __hip_bfloat16* __restrict__ hsrc,   // [NV+ZROWS, 64] (rows >= NV zero)
    const __hip_bfloat16* __restrict__ Wt,     // [27, 64, 64] (k, cout, cin) bf16
    const unsigned int* __restrict__ nbr_t,    // [27, NV] byte offsets (row*128)
    const int* __restrict__ batch_idx,         // [NV]
    const float* __restrict__ ss,              // [4, 128]
    const float* __restrict__ bias,            // [64]
    const float* __restrict__ feats,           // [NV, 64] (EPI=1)
    __hip_bfloat16* __restrict__ dst_bf, float* __restrict__ dst_f32) {
    __shared__ short sB[2][4096];  // two 8KB swizzled B buffers
    __shared__ float s_ss[512];

    int tid = threadIdx.x, lane = tid & 63, wave = tid >> 6;
    int l15 = lane & 15, quad = lane >> 4;
    int roww = blockIdx.x * 128 + wave * 32;

    if (EPI == 0) {
        s_ss[tid] = ss[tid];
        s_ss[tid + 256] = ss[tid + 256];
    }

    const char* hb = (const char*)hsrc;
    const short8* w8 = (const short8*)Wt;
    char* sbase = (char*)sB;

    // staging positions (XOR swizzle: chunk c -> row*8 + ((c&7)^(row&7)))
    int c0 = tid, c1 = tid + 256;
    int pw0 = (((c0 >> 3) * 8) + ((c0 & 7) ^ ((c0 >> 3) & 7))) * 16;
    int pw1 = (((c1 >> 3) * 8) + ((c1 & 7) ^ ((c1 >> 3) & 7))) * 16;
    // read vaddrs: byte = l15*128 + ((ks*4+quad)^(l15&7))*16  (+ n*2048 + buf*8192 imm)
    int e7 = l15 & 7;
    int va0 = l15 * 128 + ((quad ^ e7) & 7) * 16;
    int va1 = l15 * 128 + (((4 | quad) ^ e7) & 7) * 16;

    const unsigned int* np = nbr_t + roww + l15;
    unsigned int qoff = (unsigned int)(quad * 16);

    // prologue: idx(0),(1); A(0); B(0)->LDS; B(1)->regs
    unsigned int jc0 = np[0], jc1 = np[16];
    unsigned int jn0 = np[NV], jn1 = np[NV + 16];
    *(short8*)(sbase + pw0) = w8[c0];
    *(short8*)(sbase + pw1) = w8[c1];
    short8 Br0 = w8[512 + c0], Br1 = w8[512 + c1];
    unsigned int po0 = jc0 + qoff, po1 = jc1 + qoff;
    short8 ac00 = *(const short8*)(hb + po0);
    short8 ac01 = *(const short8*)(hb + po0 + 64);
    short8 ac10 = *(const short8*)(hb + po1);
    short8 ac11 = *(const short8*)(hb + po1 + 64);

    floatx4 acc[2][4];
#pragma unroll
    for (int m = 0; m < 2; ++m)
#pragma unroll
        for (int n = 0; n < 4; ++n) acc[m][n] = (floatx4){0.f, 0.f, 0.f, 0.f};

    __asm__ __volatile__("s_waitcnt lgkmcnt(0)" ::: "memory");
    __builtin_amdgcn_s_barrier();

#define CITER(K, CURB, OTHB)                                                              \
    {                                                                                     \
        int kp2 = ((K) + 2 < KOFF) ? (K) + 2 : KOFF - 1;                                  \
        short8 Bn0 = w8[kp2 * 512 + c0];                                                  \
        short8 Bn1 = w8[kp2 * 512 + c1];                                                  \
        unsigned int j20 = np[(size_t)kp2 * NV];                                          \
        unsigned int j21 = np[(size_t)kp2 * NV + 16];                                     \
        unsigned int o0 = jn0 + qoff, o1 = jn1 + qoff;                                    \
        short8 an00 = *(const short8*)(hb + o0);                                          \
        short8 an01 = *(const short8*)(hb + o0 + 64);                                     \
        short8 an10 = *(const short8*)(hb + o1);                                          \
        short8 an11 = *(const short8*)(hb + o1 + 64);                                     \
        short8 bf00 = *(const short8*)(sbase + (CURB) + va0 + 0 * 2048);                  \
        short8 bf01 = *(const short8*)(sbase + (CURB) + va0 + 1 * 2048);                  \
        short8 bf02 = *(const short8*)(sbase + (CURB) + va0 + 2 * 2048);                  \
        short8 bf03 = *(const short8*)(sbase + (CURB) + va0 + 3 * 2048);                  \
        short8 bf10 = *(const short8*)(sbase + (CURB) + va1 + 0 * 2048);                  \
        short8 bf11 = *(const short8*)(sbase + (CURB) + va1 + 1 * 2048);                  \
        short8 bf12 = *(const short8*)(sbase + (CURB) + va1 + 2 * 2048);                  \
        short8 bf13 = *(const short8*)(sbase + (CURB) + va1 + 3 * 2048);                  \
        *(short8*)(sbase + (OTHB) + pw0) = Br0;                                           \
        *(short8*)(sbase + (OTHB) + pw1) = Br1;                                           \
        acc[0][0] = __builtin_amdgcn_mfma_f32_16x16x32_bf16(ac00, bf00, acc[0][0], 0, 0, 0); \
        acc[0][1] = __builtin_amdgcn_mfma_f32_16x16x32_bf16(ac00, bf01, acc[0][1], 0, 0, 0); \
        acc[0][2] = __builtin_amdgcn_mfma_f32_16x16x32_bf16(ac00, bf02, acc[0][2], 0, 0, 0); \
        acc[0][3] = __builtin_amdgcn_mfma_f32_16x16x32_bf16(ac00, bf03, acc[0][3], 0, 0, 0); \
        acc[1][0] = __builtin_amdgcn_mfma_f32_16x16x32_bf16(ac10, bf00, acc[1][0], 0, 0, 0); \
        acc[1][1] = __builtin_amdgcn_mfma_f32_16x16x32_bf16(ac10, bf01, acc[1][1], 0, 0, 0); \
        acc[1][2] = __builtin_amdgcn_mfma_f32_16x16x32_bf16(ac10, bf02, acc[1][2], 0, 0, 0); \
        acc[1][3] = __builtin_amdgcn_mfma_f32_16x16x32_bf16(ac10, bf03, acc[1][3], 0, 0, 0); \
        acc[0][0] = __builtin_amdgcn_mfma_f32_16x16x32_bf16(ac01, bf10, acc[0][0], 0, 0, 0); \
        acc[0][1] = __builtin_amdgcn_mfma_f32_16x16x32_bf16(ac01, bf11, acc[0][1], 0, 0, 0); \
        acc[0][2] = __builtin_amdgcn_mfma_f32_16x16x32_bf16(ac01, bf12, acc[0][2], 0, 0, 0); \
        acc[0][3] = __builtin_amdgcn_mfma_f32_16x16x32_bf16(ac01, bf13, acc[0][3], 0, 0, 0); \
        acc[1][0] = __builtin_amdgcn_mfma_f32_16x16x32_bf16(ac11, bf10, acc[1][0], 0, 0, 0); \
        acc[1][1] = __builtin_amdgcn_mfma_f32_16x16x32_bf16(ac11, bf11, acc[1][1], 0, 0, 0); \
        acc[1][2] = __builtin_amdgcn_mfma_f32_16x16x32_bf16(ac11, bf12, acc[1][2], 0, 0, 0); \
        acc[1][3] = __builtin_amdgcn_mfma_f32_16x16x32_bf16(ac11, bf13, acc[1][3], 0, 0, 0); \
        __asm__ __volatile__("s_waitcnt lgkmcnt(0)" ::: "memory");                        \
        __builtin_amdgcn_s_barrier();                                                     \
        ac00 = an00; ac01 = an01; ac10 = an10; ac11 = an11;                               \
        Br0 = Bn0; Br1 = Bn1; jn0 = j20; jn1 = j21;                                       \
    }

#pragma unroll 1
    for (int k = 0; k < KOFF - 1; k += 2) {
        CITER(k, 0, 8192);
        CITER(k + 1, 8192, 0);
    }
    CITER(KOFF - 1, 0, 8192);
#undef CITER

    // epilogue: C/D layout col = lane&15, row = quad*4 + r
    float bias_v[4];
#pragma unroll
    for (int n = 0; n < 4; ++n) bias_v[n] = bias[n * 16 + l15];

#pragma unroll
    for (int m = 0; m < 2; ++m) {
#pragma unroll
        for (int r = 0; r < 4; ++r) {
            int row = roww + m * 16 + quad * 4 + r;
            float v[4];
#pragma unroll
            for (int n = 0; n < 4; ++n) v[n] = acc[m][n][r] + bias_v[n];
            if (EPI == 0) {
                float s = v[0] + v[1] + v[2] + v[3];
                float q = v[0] * v[0] + v[1] * v[1] + v[2] * v[2] + v[3] * v[3];
#pragma unroll
                for (int msk = 1; msk < 16; msk <<= 1) {
                    s += __shfl_xor(s, msk);
                    q += __shfl_xor(q, msk);
                }
                float mu = s * (1.0f / 64.0f);
                float var = q * (1.0f / 64.0f) - mu * mu;
                float inv = rsqrtf(var + 1e-6f);
                int b = batch_idx[row];
                const float* sb = s_ss + b * 128;
#pragma unroll
                for (int n = 0; n < 4; ++n) {
                    float hn = (v[n] - mu) * inv;
                    float x = hn * (1.0f + sb[n * 16 + l15]) + sb[64 + n * 16 + l15];
                    dst_bf[row * 64 + n * 16 + l15] = __float2bfloat16(silu_f(x));
                }
            } else {
#pragma unroll
                for (int n = 0; n < 4; ++n)
                    dst_f32[row * 64 + n * 16 + l15] = v[n] + feats[row * 64 + n * 16 + l15];
            }
        }
    }
}

extern "C" void kernel_launch(void* const* d_in, const int* in_sizes, int n_in,
                              void* d_out, int out_size, void* d_ws, size_t ws_size,
                              hipStream_t stream) {
    (void)in_sizes; (void)n_in; (void)out_size; (void)ws_size;
    const float* feats = (const float*)d_in[0];
    const float* emb   = (const float*)d_in[1];
    const float* gamma = (const float*)d_in[2];
    const float* beta  = (const float*)d_in[3];
    const float* W1    = (const float*)d_in[4];
    const float* b1    = (const float*)d_in[5];
    const float* W2    = (const float*)d_in[6];
    const float* b2    = (const float*)d_in[7];
    const float* emb_W = (const float*)d_in[8];
    const float* emb_b = (const float*)d_in[9];
    const int* nbr     = (const int*)d_in[10];
    const int* bidx    = (const int*)d_in[11];
    float* out = (float*)d_out;

    const size_t HSZ = (size_t)(NV + ZROWS) * 64 * 2;  // bf16 buffer with zero region
    char* ws = (char*)d_ws;
    __hip_bfloat16* W1t = (__hip_bfloat16*)(ws);                  // 221184 B
    __hip_bfloat16* W2t = (__hip_bfloat16*)(ws + 221184);         // 221184 B
    float* ss           = (float*)(ws + 442368);                  // 2048 B
    __hip_bfloat16* h0  = (__hip_bfloat16*)(ws + 444416);
    __hip_bfloat16* h2  = (__hip_bfloat16*)(ws + 444416 + HSZ);
    unsigned int* nbr_t = (unsigned int*)(ws + 444416 + 2 * HSZ); // [27,NV] byte offsets

    pre_kernel<<<3122, 256, 0, stream>>>(feats, emb, gamma, beta, W1, W2, emb_W, emb_b,
                                         nbr, W1t, W2t, ss, h0, h2, nbr_t);
    conv_kernel<0><<<1024, 256, 0, stream>>>(h0, W1t, nbr_t, bidx, ss, b1, nullptr, h2, nullptr);
    conv_kernel<1><<<1024, 256, 0, stream>>>(h2, W2t, nbr_t, bidx, ss, b2, feats, nullptr, out);
}